// Round 1
// baseline (93.706 us; speedup 1.0000x reference)
//
#include <hip/hip_runtime.h>
#include <math.h>

// Problem constants
#define NPIX   (512 * 3072)     // 1,572,864 pixels (= flat x length)
#define NCLS   10
#define NLAYER 3
#define PI_4   0.78539816339744830962f

// ---------------------------------------------------------------------------
// Kernel A: one block. Evaluate the reference circuit at 8 sample angles
// x_k = k*pi/4 per class, then 8-point real DFT -> 7 Fourier coefficients
// per class (|s0|^2 is exactly band-limited to 3rd harmonic in x).
// coef layout in ws: [class][7] = {a0, a1, a2, a3, b1, b2, b3}
// ---------------------------------------------------------------------------
__global__ void coef_kernel(const float* __restrict__ params,
                            float* __restrict__ ws) {
    __shared__ float y[NCLS][8];
    const int t = threadIdx.x;

    if (t < NCLS * 8) {
        const int c = t >> 3;
        const int k = t & 7;
        const float x = (float)k * PI_4;

        // state |0>
        float s0r = 1.f, s0i = 0.f, s1r = 0.f, s1i = 0.f;

        #pragma unroll
        for (int l = 0; l < NLAYER; ++l) {
            // Ry(x): half-angle x/2
            {
                float sh, ch;
                sincosf(0.5f * x, &sh, &ch);
                float n0r = ch * s0r - sh * s1r;
                float n0i = ch * s0i - sh * s1i;
                float n1r = sh * s0r + ch * s1r;
                float n1i = sh * s0i + ch * s1i;
                s0r = n0r; s0i = n0i; s1r = n1r; s1i = n1i;
            }
            // Rz(g0): s0 *= e^{-i th}, s1 *= e^{+i th}
            {
                float th = 0.5f * params[(c * NLAYER + l) * 3 + 0];
                float st, ct;
                sincosf(th, &st, &ct);
                float n0r = s0r * ct + s0i * st;
                float n0i = s0i * ct - s0r * st;
                float n1r = s1r * ct - s1i * st;
                float n1i = s1i * ct + s1r * st;
                s0r = n0r; s0i = n0i; s1r = n1r; s1i = n1i;
            }
            // Ry(g1)
            {
                float th = 0.5f * params[(c * NLAYER + l) * 3 + 1];
                float sh, ch;
                sincosf(th, &sh, &ch);
                float n0r = ch * s0r - sh * s1r;
                float n0i = ch * s0i - sh * s1i;
                float n1r = sh * s0r + ch * s1r;
                float n1i = sh * s0i + ch * s1i;
                s0r = n0r; s0i = n0i; s1r = n1r; s1i = n1i;
            }
            // Rz(g2)
            {
                float th = 0.5f * params[(c * NLAYER + l) * 3 + 2];
                float st, ct;
                sincosf(th, &st, &ct);
                float n0r = s0r * ct + s0i * st;
                float n0i = s0i * ct - s0r * st;
                float n1r = s1r * ct - s1i * st;
                float n1i = s1i * ct + s1r * st;
                s0r = n0r; s0i = n0i; s1r = n1r; s1i = n1i;
            }
        }
        y[c][k] = s0r * s0r + s0i * s0i;
    }

    __syncthreads();

    if (t < NCLS * 7) {
        const int c = t / 7;
        const int j = t % 7;
        float acc = 0.f;
        #pragma unroll
        for (int k = 0; k < 8; ++k) {
            const float ang = (float)k * PI_4;
            float w;
            if (j == 0)       w = 0.125f;
            else if (j <= 3)  w = 0.25f * cosf((float)j * ang);
            else              w = 0.25f * sinf((float)(j - 3) * ang);
            acc += y[c][k] * w;
        }
        ws[c * 7 + j] = acc;
    }
}

// ---------------------------------------------------------------------------
// Kernel B: memory-bound reconstruction. Each thread handles 4 pixels
// (float4 x load, 10x float4 out stores = 160 contiguous bytes/thread).
// out[p*10 + c] = a0 + a1 c1 + a2 c2 + a3 c3 + b1 s1 + b2 s2 + b3 s3
// Coefficients are grid-uniform -> scalar (s_load) reads, SGPR operands.
// ---------------------------------------------------------------------------
__global__ __launch_bounds__(256) void eval_kernel(const float* __restrict__ x,
                                                   const float* __restrict__ coef,
                                                   float* __restrict__ out) {
    const int g = blockIdx.x * 256 + threadIdx.x;   // group of 4 pixels

    const float4 xv = ((const float4* __restrict__)x)[g];
    const float px[4] = {xv.x, xv.y, xv.z, xv.w};

    // uniform coefficient load (expected to become s_load_dwordx* -> SGPRs)
    float cf[NCLS * 7];
    #pragma unroll
    for (int i = 0; i < NCLS * 7; ++i) cf[i] = coef[i];

    float r[40];
    #pragma unroll
    for (int p = 0; p < 4; ++p) {
        float s1, c1;
        sincosf(px[p], &s1, &c1);
        const float c2 = 2.f * c1 * c1 - 1.f;
        const float s2 = 2.f * s1 * c1;
        const float c3 = c1 * c2 - s1 * s2;
        const float s3 = s1 * c2 + c1 * s2;
        #pragma unroll
        for (int c = 0; c < NCLS; ++c) {
            const float* f = &cf[c * 7];
            r[p * 10 + c] = f[0] + f[1] * c1 + f[2] * c2 + f[3] * c3
                                 + f[4] * s1 + f[5] * s2 + f[6] * s3;
        }
    }

    // 40 floats = 160 bytes contiguous per thread; base is 16B-aligned.
    float4* op = (float4*)(out + (size_t)g * 40);
    #pragma unroll
    for (int i = 0; i < 10; ++i) op[i] = ((const float4*)r)[i];
}

extern "C" void kernel_launch(void* const* d_in, const int* in_sizes, int n_in,
                              void* d_out, int out_size, void* d_ws, size_t ws_size,
                              hipStream_t stream) {
    const float* x      = (const float*)d_in[0];   // [512*3*32*32] fp32
    const float* params = (const float*)d_in[1];   // [10*3*3] fp32
    float* out          = (float*)d_out;           // [512*3072*10] fp32
    float* coef         = (float*)d_ws;            // 70 floats scratch

    coef_kernel<<<1, 128, 0, stream>>>(params, coef);

    const int groups = NPIX / 4;                   // 393,216
    const int blocks = groups / 256;               // 1,536 (exact)
    eval_kernel<<<blocks, 256, 0, stream>>>(x, coef, out);
}

// Round 2
// 82.589 us; speedup vs baseline: 1.1346x; 1.1346x over previous
//
#include <hip/hip_runtime.h>
#include <math.h>

// Problem constants
#define NPIX   (512 * 3072)     // 1,572,864 pixels (= flat x length)
#define NCLS   10
#define NLAYER 3
#define PI_4   0.78539816339744830962f

// ---------------------------------------------------------------------------
// Kernel A: one block. Evaluate the reference circuit at 8 sample angles
// x_k = k*pi/4 per class, then 8-point real DFT -> 7 Fourier coefficients
// per class (|s0|^2 is exactly band-limited to 3rd harmonic in x).
// coef layout in ws: [class][7] = {a0, a1, a2, a3, b1, b2, b3}
// ---------------------------------------------------------------------------
__global__ void coef_kernel(const float* __restrict__ params,
                            float* __restrict__ ws) {
    __shared__ float y[NCLS][8];
    const int t = threadIdx.x;

    if (t < NCLS * 8) {
        const int c = t >> 3;
        const int k = t & 7;
        const float x = (float)k * PI_4;

        float s0r = 1.f, s0i = 0.f, s1r = 0.f, s1i = 0.f;

        #pragma unroll
        for (int l = 0; l < NLAYER; ++l) {
            // Ry(x)
            {
                float sh, ch;
                sincosf(0.5f * x, &sh, &ch);
                float n0r = ch * s0r - sh * s1r;
                float n0i = ch * s0i - sh * s1i;
                float n1r = sh * s0r + ch * s1r;
                float n1i = sh * s0i + ch * s1i;
                s0r = n0r; s0i = n0i; s1r = n1r; s1i = n1i;
            }
            // Rz(g0)
            {
                float th = 0.5f * params[(c * NLAYER + l) * 3 + 0];
                float st, ct;
                sincosf(th, &st, &ct);
                float n0r = s0r * ct + s0i * st;
                float n0i = s0i * ct - s0r * st;
                float n1r = s1r * ct - s1i * st;
                float n1i = s1i * ct + s1r * st;
                s0r = n0r; s0i = n0i; s1r = n1r; s1i = n1i;
            }
            // Ry(g1)
            {
                float th = 0.5f * params[(c * NLAYER + l) * 3 + 1];
                float sh, ch;
                sincosf(th, &sh, &ch);
                float n0r = ch * s0r - sh * s1r;
                float n0i = ch * s0i - sh * s1i;
                float n1r = sh * s0r + ch * s1r;
                float n1i = sh * s0i + ch * s1i;
                s0r = n0r; s0i = n0i; s1r = n1r; s1i = n1i;
            }
            // Rz(g2)
            {
                float th = 0.5f * params[(c * NLAYER + l) * 3 + 2];
                float st, ct;
                sincosf(th, &st, &ct);
                float n0r = s0r * ct + s0i * st;
                float n0i = s0i * ct - s0r * st;
                float n1r = s1r * ct - s1i * st;
                float n1i = s1i * ct + s1r * st;
                s0r = n0r; s0i = n0i; s1r = n1r; s1i = n1i;
            }
        }
        y[c][k] = s0r * s0r + s0i * s0i;
    }

    __syncthreads();

    if (t < NCLS * 7) {
        const int c = t / 7;
        const int j = t % 7;
        float acc = 0.f;
        #pragma unroll
        for (int k = 0; k < 8; ++k) {
            const float ang = (float)k * PI_4;
            float w;
            if (j == 0)       w = 0.125f;
            else if (j <= 3)  w = 0.25f * cosf((float)j * ang);
            else              w = 0.25f * sinf((float)(j - 3) * ang);
            acc += y[c][k] * w;
        }
        ws[c * 7 + j] = acc;
    }
}

// ---------------------------------------------------------------------------
// Kernel B: write-roofline reconstruction with LDS-staged coalesced stores.
// Block = 256 threads; each thread computes 2 pixels (20 floats) into LDS,
// then the block streams the 20 KB tile out as 5 rounds of contiguous
// wave-wide float4 stores (1 KB per store instruction).
//   out[p*10 + c] = a0 + a1 c1 + a2 c2 + a3 c3 + b1 s1 + b2 s2 + b3 s3
// Coefficients are grid-uniform -> scalar loads, SGPR operands.
// ---------------------------------------------------------------------------
__global__ __launch_bounds__(256) void eval_kernel(const float* __restrict__ x,
                                                   const float* __restrict__ coef,
                                                   float* __restrict__ out) {
    __shared__ float lds[256 * 20];                 // 20 KB: 512 pixels x 10

    const int t = threadIdx.x;
    const int g = blockIdx.x * 256 + t;             // pixel-pair index

    // coalesced input: 2 pixels per thread (8 B/lane)
    const float2 xv = ((const float2* __restrict__)x)[g];
    const float px[2] = {xv.x, xv.y};

    // uniform coefficient load -> SGPRs
    float cf[NCLS * 7];
    #pragma unroll
    for (int i = 0; i < NCLS * 7; ++i) cf[i] = coef[i];

    float r[20];
    #pragma unroll
    for (int p = 0; p < 2; ++p) {
        float s1, c1;
        sincosf(px[p], &s1, &c1);
        const float c2 = 2.f * c1 * c1 - 1.f;
        const float s2 = 2.f * s1 * c1;
        const float c3 = c1 * c2 - s1 * s2;
        const float s3 = s1 * c2 + c1 * s2;
        #pragma unroll
        for (int c = 0; c < NCLS; ++c) {
            const float* f = &cf[c * 7];
            r[p * 10 + c] = f[0] + f[1] * c1 + f[2] * c2 + f[3] * c3
                                 + f[4] * s1 + f[5] * s2 + f[6] * s3;
        }
    }

    // stage to LDS: 5x ds_write_b128 at 80 B lane stride (2-way alias = free)
    float4* wb = (float4*)&lds[t * 20];
    #pragma unroll
    for (int i = 0; i < 5; ++i) wb[i] = ((const float4*)r)[i];

    __syncthreads();

    // stream out: 5 rounds of contiguous wave-wide float4 stores
    float4* o4 = (float4*)out + (size_t)blockIdx.x * 1280;   // 5120 floats/block
    const float4* l4 = (const float4*)lds;
    #pragma unroll
    for (int i = 0; i < 5; ++i) o4[i * 256 + t] = l4[i * 256 + t];
}

extern "C" void kernel_launch(void* const* d_in, const int* in_sizes, int n_in,
                              void* d_out, int out_size, void* d_ws, size_t ws_size,
                              hipStream_t stream) {
    const float* x      = (const float*)d_in[0];   // [512*3*32*32] fp32
    const float* params = (const float*)d_in[1];   // [10*3*3] fp32
    float* out          = (float*)d_out;           // [512*3072*10] fp32
    float* coef         = (float*)d_ws;            // 70 floats scratch

    coef_kernel<<<1, 128, 0, stream>>>(params, coef);

    const int pairs  = NPIX / 2;                   // 786,432 pixel pairs
    const int blocks = pairs / 256;                // 3,072 (exact)
    eval_kernel<<<blocks, 256, 0, stream>>>(x, coef, out);
}